// Round 4
// baseline (3464.312 us; speedup 1.0000x reference)
//
#include <hip/hip_runtime.h>
#include <hip/hip_bf16.h>
#include <cstdint>
#include <cstddef>

typedef unsigned short u16;
using frag  = __attribute__((ext_vector_type(8))) short;   // 8 x bf16
using f32x4 = __attribute__((ext_vector_type(4))) float;   // 4 x fp32 acc

#define DEV __device__ __forceinline__

DEV float bf2f(u16 u) { union { unsigned int i; float f; } x; x.i = ((unsigned int)u) << 16; return x.f; }
DEV u16 f2bf(float f) {
  union { float f; unsigned int i; } x; x.f = f;
  unsigned int r = x.i + 0x7fffu + ((x.i >> 16) & 1u);
  return (u16)(r >> 16);
}

#define MFMA16(a, b, c) __builtin_amdgcn_mfma_f32_16x16x32_bf16((a), (b), (c), 0, 0, 0)

// B=32 N=576 D=768 H=8 HD=96 MLP=3072 L=2 GRID=24 SD=64
#define SB   32
#define SN   576
#define SD_  768
#define SH   8
#define SHD  96
#define SMLP 3072
#define BN_  (SB * SN)          // 18432 rows
#define IMG  (SN * SD_)         // 442368

// ---- bf16 param-mirror block offsets (elements) ----
#define P_RE   0
#define P_CE   768
#define P_PW   1536
#define P_PB   50688
#define P_REL  51456
#define P_L1G  53696
#define P_L1B  55232
#define P_L2G  56768
#define P_L2B  58304
#define P_BQ   59840
#define P_BK   61376
#define P_BV   62912
#define P_BO   64448
#define P_B1   65984
#define P_B2   72128
#define P_TOT  73664

// ---------------- dtype detect: ln1_g[0] == 1.0 exactly ----------------
// fp32: first u32 = 0x3F800000 ; bf16: two u16 0x3F80 -> u32 0x3F803F80
__global__ void detect_kernel(const void* probe, int* flag) {
  if (threadIdx.x == 0 && blockIdx.x == 0) {
    unsigned int w = *(const unsigned int*)probe;
    flag[0] = (w == 0x3F800000u) ? 1 : 0;   // 1 => inputs are fp32
  }
}

// ---------------- canonicalize all small params into bf16 mirror block ----------------
__global__ void canon_params(const void* re, const void* ce, const void* pw, const void* pb,
                             const void* rel, const void* l1g, const void* l1b,
                             const void* l2g, const void* l2b,
                             const void* pbq, const void* pbk, const void* pbv, const void* pbo,
                             const void* pb1, const void* pb2,
                             u16* __restrict__ P, const int* __restrict__ flag) {
  int i = blockIdx.x * 256 + threadIdx.x;
  const void* src; int si;
  if      (i < 768)     { src = re;  si = i; }
  else if (i < 1536)    { src = ce;  si = i - 768; }
  else if (i < 50688)   { src = pw;  si = i - 1536; }
  else if (i < 51456)   { src = pb;  si = i - 50688; }
  else if (i < 53665)   { src = rel; si = i - 51456; }
  else if (i < P_L1G)   { return; }
  else if (i < P_L1B)   { src = l1g; si = i - P_L1G; }
  else if (i < P_L2G)   { src = l1b; si = i - P_L1B; }
  else if (i < P_L2B)   { src = l2g; si = i - P_L2G; }
  else if (i < P_BQ)    { src = l2b; si = i - P_L2B; }
  else if (i < P_BK)    { src = pbq; si = i - P_BQ; }
  else if (i < P_BV)    { src = pbk; si = i - P_BK; }
  else if (i < P_BO)    { src = pbv; si = i - P_BV; }
  else if (i < P_B1)    { src = pbo; si = i - P_BO; }
  else if (i < P_B2)    { src = pb1; si = i - P_B1; }
  else if (i < P_TOT)   { src = pb2; si = i - P_B2; }
  else return;
  P[i] = flag[0] ? f2bf(((const float*)src)[si]) : ((const u16*)src)[si];
}

// ---------------- positional encoding (from bf16 mirror) ----------------
__global__ void posenc_kernel(const u16* __restrict__ P, float* __restrict__ pe) {
  int n = blockIdx.x;
  int r = n / 24, c = n % 24;
  const u16* re = P + P_RE;
  const u16* ce = P + P_CE;
  const u16* pw = P + P_PW;
  const u16* pb = P + P_PB;
  for (int d = threadIdx.x; d < SD_; d += 256) {
    float acc = bf2f(pb[d]);
    for (int s = 0; s < 32; ++s) {
      acc += bf2f(re[r * 32 + s]) * bf2f(pw[s * SD_ + d]);
      acc += bf2f(ce[c * 32 + s]) * bf2f(pw[(32 + s) * SD_ + d]);
    }
    pe[n * SD_ + d] = acc;
  }
}

// ---------------- relative position bias table [576][576] fp32 ----------------
__global__ void bias_kernel(const u16* __restrict__ P, float* __restrict__ biasT) {
  int i = blockIdx.x * 256 + threadIdx.x;
  if (i < SN * SN) {
    int qi = i / SN, kj = i % SN;
    int ri = qi / 24, ci = qi % 24, rj = kj / 24, cj = kj % 24;
    int idx = (ri - rj + 23) * 47 + (ci - cj + 23);
    biasT[i] = bf2f(P[P_REL + idx]);
  }
}

// ---------------- X = x + pe (fp32 residual), dual-dtype x ----------------
__global__ void xinit_kernel(const void* __restrict__ xin, const float* __restrict__ pe,
                             float* __restrict__ X, const int* __restrict__ flag) {
  int idx = (blockIdx.x * 256 + threadIdx.x) * 4;
  int b = blockIdx.y;
  float vx, vy, vz, vw;
  if (flag[0]) {
    float4 t = *(const float4*)((const float*)xin + (size_t)b * IMG + idx);
    vx = t.x; vy = t.y; vz = t.z; vw = t.w;
  } else {
    ushort4 t = *(const ushort4*)((const u16*)xin + (size_t)b * IMG + idx);
    vx = bf2f(t.x); vy = bf2f(t.y); vz = bf2f(t.z); vw = bf2f(t.w);
  }
  float4 p = *(const float4*)(pe + idx);
  float4 o;
  o.x = vx + p.x; o.y = vy + p.y; o.z = vz + p.z; o.w = vw + p.w;
  *(float4*)(X + (size_t)b * IMG + idx) = o;
}

// ---------------- weight transpose (dual-dtype): W[K][N] -> Wt[N][K] bf16 ----------------
__global__ void transpose_any(const void* __restrict__ W, size_t eOff,
                              u16* __restrict__ Wt, int K, int N,
                              const int* __restrict__ flag) {
  __shared__ u16 tile[64][65];
  const int fp32 = flag[0];
  int n0 = blockIdx.x * 64, k0 = blockIdx.y * 64;
  int tx = threadIdx.x, ty = threadIdx.y;
#pragma unroll
  for (int j = 0; j < 16; ++j) {
    int k = ty + 4 * j;
    size_t si = eOff + (size_t)(k0 + k) * N + n0 + tx;
    tile[k][tx] = fp32 ? f2bf(((const float*)W)[si]) : ((const u16*)W)[si];
  }
  __syncthreads();
#pragma unroll
  for (int j = 0; j < 16; ++j) {
    int n = ty + 4 * j;
    Wt[(size_t)(n0 + n) * K + k0 + tx] = tile[tx][n];
  }
}

// ---------------- LayerNorm: fp32 X row -> bf16 (g/b from mirror) ----------------
__global__ __launch_bounds__(256) void ln_kernel(const float* __restrict__ X,
                                                 const u16* __restrict__ g,
                                                 const u16* __restrict__ bb,
                                                 u16* __restrict__ Outn) {
  int row = blockIdx.x * 4 + (threadIdx.x >> 6);
  int lane = threadIdx.x & 63;
  const float* xr = X + (size_t)row * SD_;
  float4 v[3];
  float s = 0.f, sq = 0.f;
#pragma unroll
  for (int i = 0; i < 3; ++i) {
    v[i] = *(const float4*)(xr + i * 256 + lane * 4);
    s += v[i].x + v[i].y + v[i].z + v[i].w;
    sq += v[i].x * v[i].x + v[i].y * v[i].y + v[i].z * v[i].z + v[i].w * v[i].w;
  }
#pragma unroll
  for (int o = 1; o < 64; o <<= 1) {
    s += __shfl_xor(s, o, 64);
    sq += __shfl_xor(sq, o, 64);
  }
  float mean = s * (1.0f / 768.0f);
  float var = sq * (1.0f / 768.0f) - mean * mean;
  float rstd = rsqrtf(fmaxf(var, 0.f) + 1e-5f);
  u16* orow = Outn + (size_t)row * SD_;
#pragma unroll
  for (int i = 0; i < 3; ++i) {
    int d = i * 256 + lane * 4;
    ushort4 gv = *(const ushort4*)(g + d);
    ushort4 bv = *(const ushort4*)(bb + d);
    ushort4 ov;
    ov.x = f2bf((v[i].x - mean) * rstd * bf2f(gv.x) + bf2f(bv.x));
    ov.y = f2bf((v[i].y - mean) * rstd * bf2f(gv.y) + bf2f(bv.y));
    ov.z = f2bf((v[i].z - mean) * rstd * bf2f(gv.z) + bf2f(bv.z));
    ov.w = f2bf((v[i].w - mean) * rstd * bf2f(gv.w) + bf2f(bv.w));
    *(ushort4*)(orow + d) = ov;
  }
}

// ---------------- GEMM: C = A[M,K] @ Bt[N,K]^T ----------------
// mode 0: Out=bf16(C+bias)  1: Out=bf16(gelu_exact(C+bias))  2: Xres += C+bias (fp32)
__global__ __launch_bounds__(256) void gemm_bt(const u16* __restrict__ A,
                                               const u16* __restrict__ Bt,
                                               const u16* __restrict__ bias,
                                               u16* __restrict__ Out,
                                               float* __restrict__ Xres,
                                               int Ncols, int K, int mode) {
  __shared__ __align__(16) u16 As[128 * 32];
  __shared__ __align__(16) u16 Bs[128 * 32];
  const int tid = threadIdx.x;
  const int lane = tid & 63;
  const int wave = tid >> 6;
  const int wm = wave & 1, wn = wave >> 1;
  const int bn = blockIdx.x, bm = blockIdx.y;
  const int m16 = lane & 15, q8 = (lane >> 4) * 8;
  f32x4 acc[4][4] = {};
  const size_t Abase = (size_t)(bm * 128) * K;
  const size_t Bbase = (size_t)(bn * 128) * K;

  for (int kb = 0; kb < K; kb += 32) {
    __syncthreads();
#pragma unroll
    for (int i = 0; i < 2; ++i) {
      int c = tid + i * 256;
      int row = c >> 2, ko = (c & 3) * 8;
      *(uint4*)(As + row * 32 + ko) = *(const uint4*)(A + Abase + (size_t)row * K + kb + ko);
      *(uint4*)(Bs + row * 32 + ko) = *(const uint4*)(Bt + Bbase + (size_t)row * K + kb + ko);
    }
    __syncthreads();
    frag af[4], bf[4];
#pragma unroll
    for (int t = 0; t < 4; ++t)
      af[t] = *(const frag*)(As + (wm * 64 + t * 16 + m16) * 32 + q8);
#pragma unroll
    for (int t = 0; t < 4; ++t)
      bf[t] = *(const frag*)(Bs + (wn * 64 + t * 16 + m16) * 32 + q8);
#pragma unroll
    for (int i = 0; i < 4; ++i)
#pragma unroll
      for (int j = 0; j < 4; ++j)
        acc[i][j] = MFMA16(af[i], bf[j], acc[i][j]);
  }

  const int r4 = (lane >> 4) * 4;
#pragma unroll
  for (int j = 0; j < 4; ++j) {
    int col = bn * 128 + wn * 64 + j * 16 + m16;
    float bv = bf2f(bias[col]);
#pragma unroll
    for (int i = 0; i < 4; ++i) {
      int row0 = bm * 128 + wm * 64 + i * 16 + r4;
#pragma unroll
      for (int r = 0; r < 4; ++r) {
        float v = acc[i][j][r] + bv;
        size_t off = (size_t)(row0 + r) * Ncols + col;
        if (mode == 0) {
          Out[off] = f2bf(v);
        } else if (mode == 1) {
          v = 0.5f * v * (1.0f + erff(v * 0.70710678118654752f));
          Out[off] = f2bf(v);
        } else {
          Xres[off] += v;
        }
      }
    }
  }
}

// ---------------- attention: block = (q-tile, head, local batch) ----------------
__global__ __launch_bounds__(256) void attn_kernel(const u16* __restrict__ Q,
                                                   const u16* __restrict__ Kb,
                                                   const u16* __restrict__ Vb,
                                                   const float* __restrict__ biasT,
                                                   u16* __restrict__ Out) {
  __shared__ __align__(16) u16 S[32 * 584];
  __shared__ __align__(16) u16 Qs[32 * 104];
  __shared__ __align__(16) u16 KV[96 * 72];
  __shared__ float rsum[32];
  const int tid = threadIdx.x, lane = tid & 63, wave = tid >> 6;
  const int qt = blockIdx.x, h = blockIdx.y, b = blockIdx.z;
  const int q0 = qt * 32;
  const int m16 = lane & 15, qd = lane >> 4;
  const float scale = 0.10206207261596575f; // 96^-0.5

  const size_t qbase = ((size_t)(b * SN + q0)) * SD_ + h * SHD;
  for (int c = tid; c < 384; c += 256) {
    int row = c / 12, off = c % 12;
    *(uint4*)(Qs + row * 104 + off * 8) = *(const uint4*)(Q + qbase + (size_t)row * SD_ + off * 8);
  }

  for (int kt = 0; kt < 9; ++kt) {
    __syncthreads();
    const size_t kbase = ((size_t)(b * SN + kt * 64)) * SD_ + h * SHD;
    for (int c = tid; c < 768; c += 256) {
      int row = c / 12, off = c % 12;
      *(uint4*)(KV + row * 104 + off * 8) = *(const uint4*)(Kb + kbase + (size_t)row * SD_ + off * 8);
    }
    __syncthreads();
    f32x4 a0 = {}, a1 = {};
#pragma unroll
    for (int ks = 0; ks < 3; ++ks) {
      frag fq0 = *(const frag*)(Qs + m16 * 104 + ks * 32 + qd * 8);
      frag fq1 = *(const frag*)(Qs + (16 + m16) * 104 + ks * 32 + qd * 8);
      frag fk = *(const frag*)(KV + (wave * 16 + m16) * 104 + ks * 32 + qd * 8);
      a0 = MFMA16(fq0, fk, a0);
      a1 = MFMA16(fq1, fk, a1);
    }
    int col = kt * 64 + wave * 16 + m16;
#pragma unroll
    for (int r = 0; r < 4; ++r) {
      S[(qd * 4 + r) * 584 + col] = f2bf(a0[r]);
      S[(16 + qd * 4 + r) * 584 + col] = f2bf(a1[r]);
    }
  }
  __syncthreads();

  {
    int row = tid >> 3, g = tid & 7;
    const float* brow = biasT + (size_t)(q0 + row) * SN;
    float mx = -1e30f;
    for (int i = 0; i < 72; ++i) {
      int j = g + i * 8;
      float s = bf2f(S[row * 584 + j]) * scale + brow[j];
      mx = fmaxf(mx, s);
    }
#pragma unroll
    for (int o = 1; o < 8; o <<= 1) mx = fmaxf(mx, __shfl_xor(mx, o, 64));
    float sum = 0.f;
    for (int i = 0; i < 72; ++i) {
      int j = g + i * 8;
      float s = bf2f(S[row * 584 + j]) * scale + brow[j];
      float e = __expf(s - mx);
      sum += e;
      S[row * 584 + j] = f2bf(e);
    }
#pragma unroll
    for (int o = 1; o < 8; o <<= 1) sum += __shfl_xor(sum, o, 64);
    if (g == 0) rsum[row] = sum;
  }

  f32x4 oacc[3] = {};
  const int rt = wave & 1, cbase = (wave >> 1) * 3;
  for (int kt = 0; kt < 9; ++kt) {
    __syncthreads();
    const size_t vbase = ((size_t)(b * SN + kt * 64)) * SD_ + h * SHD;
    for (int c = tid; c < 768; c += 256) {
      int key = c / 12, off = c % 12;
      uint4 u = *(const uint4*)(Vb + vbase + (size_t)key * SD_ + off * 8);
      int d0 = off * 8;
      KV[(d0 + 0) * 72 + key] = (u16)(u.x & 0xffff);
      KV[(d0 + 1) * 72 + key] = (u16)(u.x >> 16);
      KV[(d0 + 2) * 72 + key] = (u16)(u.y & 0xffff);
      KV[(d0 + 3) * 72 + key] = (u16)(u.y >> 16);
      KV[(d0 + 4) * 72 + key] = (u16)(u.z & 0xffff);
      KV[(d0 + 5) * 72 + key] = (u16)(u.z >> 16);
      KV[(d0 + 6) * 72 + key] = (u16)(u.w & 0xffff);
      KV[(d0 + 7) * 72 + key] = (u16)(u.w >> 16);
    }
    __syncthreads();
#pragma unroll
    for (int ch = 0; ch < 2; ++ch) {
      frag ap = *(const frag*)(S + (rt * 16 + m16) * 584 + kt * 64 + ch * 32 + qd * 8);
#pragma unroll
      for (int c = 0; c < 3; ++c) {
        frag bv = *(const frag*)(KV + ((cbase + c) * 16 + m16) * 72 + ch * 32 + qd * 8);
        oacc[c] = MFMA16(ap, bv, oacc[c]);
      }
    }
  }

#pragma unroll
  for (int c = 0; c < 3; ++c) {
#pragma unroll
    for (int r = 0; r < 4; ++r) {
      int rl = rt * 16 + qd * 4 + r;
      float inv = 1.0f / rsum[rl];
      int col = h * SHD + (cbase + c) * 16 + m16;
      Out[((size_t)(b * SN + q0 + rl)) * SD_ + col] = f2bf(oacc[c][r] * inv);
    }
  }
}

// ---------------- final output: fp32 X -> d_out in detected dtype ----------------
__global__ void castout_kernel(const float* __restrict__ X, void* __restrict__ out,
                               const int* __restrict__ flag) {
  int i = (blockIdx.x * 256 + threadIdx.x) * 4;
  float4 v = *(const float4*)(X + i);
  if (flag[0]) {
    *(float4*)((float*)out + i) = v;
  } else {
    ushort4 o;
    o.x = f2bf(v.x); o.y = f2bf(v.y); o.z = f2bf(v.z); o.w = f2bf(v.w);
    *(ushort4*)((u16*)out + i) = o;
  }
}

// ---------------- launcher ----------------
extern "C" void kernel_launch(void* const* d_in, const int* in_sizes, int n_in,
                              void* d_out, int out_size, void* d_ws, size_t ws_size,
                              hipStream_t stream) {
  const void* x_in      = d_in[0];
  const void* row_embed = d_in[1];
  const void* col_embed = d_in[2];
  const void* pos_w     = d_in[3];
  const void* pos_b     = d_in[4];
  const void* rel_bias  = d_in[5];
  const void* ln1_g = d_in[6];
  const void* ln1_b = d_in[7];
  const void* ln2_g = d_in[8];
  const void* ln2_b = d_in[9];
  const void* Wq = d_in[10];
  const void* bq = d_in[11];
  const void* Wk = d_in[12];
  const void* bk = d_in[13];
  const void* Wv = d_in[14];
  const void* bv = d_in[15];
  const void* Wo = d_in[16];
  const void* bo = d_in[17];
  const void* W1 = d_in[18];
  const void* b1 = d_in[19];
  const void* W2 = d_in[20];
  const void* b2 = d_in[21];

  const int BC = 8, RC = 4608;           // batch chunk / MLP row chunk
  const int mR = BC * SN;                // 4608 rows per attention chunk
  const size_t qkvB = (size_t)mR * SD_ * 2;
  size_t bigB = 3 * qkvB;
  { size_t hB = (size_t)RC * SMLP * 2; if (hB > bigB) bigB = hB; }

  char* ws = (char*)d_ws;
  size_t off = 0;
  auto alloc = [&](size_t bytes) -> void* {
    void* p = ws + off;
    off += (bytes + 255) & ~(size_t)255;
    return p;
  };

  int*   flag = (int*)alloc(256);
  float* X    = (float*)alloc((size_t)BN_ * SD_ * 4);   // 56.6 MB fp32 residual
  u16*   Nbuf = (u16*)alloc((size_t)RC * SD_ * 2);      // 7.1 MB LN/attn chunk buffer
  char*  big  = (char*)alloc(bigB);                      // 28.3 MB QKV chunk / MLP hidden
  u16* Qb   = (u16*)big;
  u16* Kbuf = (u16*)(big + qkvB);
  u16* Vbuf = (u16*)(big + 2 * qkvB);
  u16* Hbuf = (u16*)big;
  float* pe    = (float*)alloc((size_t)SN * SD_ * 4);
  float* biasT = (float*)alloc((size_t)SN * SN * 4);
  u16* P    = (u16*)alloc((size_t)P_TOT * 2 + 256);     // bf16 param mirror
  u16* WqT = (u16*)alloc((size_t)SD_ * SD_ * 2);
  u16* WkT = (u16*)alloc((size_t)SD_ * SD_ * 2);
  u16* WvT = (u16*)alloc((size_t)SD_ * SD_ * 2);
  u16* WoT = (u16*)alloc((size_t)SD_ * SD_ * 2);
  u16* W1T = (u16*)alloc((size_t)SD_ * SMLP * 2);
  u16* W2T = (u16*)alloc((size_t)SMLP * SD_ * 2);

  detect_kernel<<<1, 64, 0, stream>>>(ln1_g, flag);
  canon_params<<<(P_TOT + 255) / 256, 256, 0, stream>>>(
      row_embed, col_embed, pos_w, pos_b, rel_bias,
      ln1_g, ln1_b, ln2_g, ln2_b, bq, bk, bv, bo, b1, b2, P, flag);

  posenc_kernel<<<SN, 256, 0, stream>>>(P, pe);
  bias_kernel<<<(SN * SN + 255) / 256, 256, 0, stream>>>(P, biasT);
  xinit_kernel<<<dim3(IMG / 1024, SB), 256, 0, stream>>>(x_in, pe, X, flag);

  dim3 tb(64, 4);
  for (int l = 0; l < 2; ++l) {
    const size_t wOff = (size_t)l * SD_ * SD_;
    const size_t w1Off = (size_t)l * SD_ * SMLP;
    transpose_any<<<dim3(12, 12), tb, 0, stream>>>(Wq, wOff, WqT, SD_, SD_, flag);
    transpose_any<<<dim3(12, 12), tb, 0, stream>>>(Wk, wOff, WkT, SD_, SD_, flag);
    transpose_any<<<dim3(12, 12), tb, 0, stream>>>(Wv, wOff, WvT, SD_, SD_, flag);
    transpose_any<<<dim3(12, 12), tb, 0, stream>>>(Wo, wOff, WoT, SD_, SD_, flag);
    transpose_any<<<dim3(48, 12), tb, 0, stream>>>(W1, w1Off, W1T, SD_, SMLP, flag);
    transpose_any<<<dim3(12, 48), tb, 0, stream>>>(W2, w1Off, W2T, SMLP, SD_, flag);

    // attention pipeline, chunked over batch
    for (int c = 0; c < SB / BC; ++c) {
      const size_t r0 = (size_t)c * mR;
      float* Xc = X + r0 * SD_;
      ln_kernel<<<mR / 4, 256, 0, stream>>>(Xc, P + P_L1G + l * SD_, P + P_L1B + l * SD_, Nbuf);
      gemm_bt<<<dim3(6, mR / 128), 256, 0, stream>>>(Nbuf, WqT, P + P_BQ + l * SD_, Qb, nullptr, SD_, SD_, 0);
      gemm_bt<<<dim3(6, mR / 128), 256, 0, stream>>>(Nbuf, WkT, P + P_BK + l * SD_, Kbuf, nullptr, SD_, SD_, 0);
      gemm_bt<<<dim3(6, mR / 128), 256, 0, stream>>>(Nbuf, WvT, P + P_BV + l * SD_, Vbuf, nullptr, SD_, SD_, 0);
      attn_kernel<<<dim3(18, SH, BC), 256, 0, stream>>>(Qb, Kbuf, Vbuf, biasT, Nbuf);
      gemm_bt<<<dim3(6, mR / 128), 256, 0, stream>>>(Nbuf, WoT, P + P_BO + l * SD_, nullptr, Xc, SD_, SD_, 2);
    }

    // MLP, chunked over rows
    for (int c = 0; c < BN_ / RC; ++c) {
      const size_t r0 = (size_t)c * RC;
      float* Xc = X + r0 * SD_;
      ln_kernel<<<RC / 4, 256, 0, stream>>>(Xc, P + P_L2G + l * SD_, P + P_L2B + l * SD_, Nbuf);
      gemm_bt<<<dim3(24, RC / 128), 256, 0, stream>>>(Nbuf, W1T, P + P_B1 + l * SMLP, Hbuf, nullptr, SMLP, SD_, 1);
      gemm_bt<<<dim3(6, RC / 128), 256, 0, stream>>>(Hbuf, W2T, P + P_B2 + l * SD_, nullptr, Xc, SD_, SMLP, 2);
    }
  }

  castout_kernel<<<(size_t)BN_ * SD_ / 1024, 256, 0, stream>>>(X, d_out, flag);
}

// Round 5
// 2013.185 us; speedup vs baseline: 1.7208x; 1.7208x over previous
//
#include <hip/hip_runtime.h>
#include <hip/hip_bf16.h>
#include <cstdint>
#include <cstddef>

typedef unsigned short u16;
using frag  = __attribute__((ext_vector_type(8))) short;   // 8 x bf16
using f32x4 = __attribute__((ext_vector_type(4))) float;   // 4 x fp32 acc

#define DEV __device__ __forceinline__

DEV float bf2f(u16 u) { union { unsigned int i; float f; } x; x.i = ((unsigned int)u) << 16; return x.f; }
DEV u16 f2bf(float f) {
  union { float f; unsigned int i; } x; x.f = f;
  unsigned int r = x.i + 0x7fffu + ((x.i >> 16) & 1u);
  return (u16)(r >> 16);
}

#define MFMA16(a, b, c) __builtin_amdgcn_mfma_f32_16x16x32_bf16((a), (b), (c), 0, 0, 0)

// B=32 N=576 D=768 H=8 HD=96 MLP=3072 L=2 GRID=24 SD=64
#define SB   32
#define SN   576
#define SD_  768
#define SH   8
#define SHD  96
#define SMLP 3072
#define BN_  (SB * SN)          // 18432 rows
#define IMG  (SN * SD_)         // 442368
#define QKVS 2304               // fused QKV row stride

// ---- bf16 param-mirror block offsets (elements) ----
#define P_RE   0
#define P_CE   768
#define P_PW   1536
#define P_PB   50688
#define P_REL  51456
#define P_L1G  53696
#define P_L1B  55232
#define P_L2G  56768
#define P_L2B  58304
#define P_BQ   59840
#define P_BK   61376
#define P_BV   62912
#define P_BO   64448
#define P_B1   65984
#define P_B2   72128
#define P_FQB  73664            // fused qkv bias [L][2304]
#define P_TOT  78272

// ---------------- dtype detect: ln1_g[0] == 1.0 exactly ----------------
__global__ void detect_kernel(const void* probe, int* flag) {
  if (threadIdx.x == 0 && blockIdx.x == 0) {
    unsigned int w = *(const unsigned int*)probe;
    flag[0] = (w == 0x3F800000u) ? 1 : 0;   // 1 => inputs are fp32
  }
}

// ---------------- canonicalize small params into bf16 mirror ----------------
__global__ void canon_params(const void* re, const void* ce, const void* pw, const void* pb,
                             const void* rel, const void* l1g, const void* l1b,
                             const void* l2g, const void* l2b,
                             const void* pbq, const void* pbk, const void* pbv, const void* pbo,
                             const void* pb1, const void* pb2,
                             u16* __restrict__ P, const int* __restrict__ flag) {
  int i = blockIdx.x * 256 + threadIdx.x;
  const void* src; int si;
  if      (i < 768)     { src = re;  si = i; }
  else if (i < 1536)    { src = ce;  si = i - 768; }
  else if (i < 50688)   { src = pw;  si = i - 1536; }
  else if (i < 51456)   { src = pb;  si = i - 50688; }
  else if (i < 53665)   { src = rel; si = i - 51456; }
  else if (i < P_L1G)   { return; }
  else if (i < P_L1B)   { src = l1g; si = i - P_L1G; }
  else if (i < P_L2G)   { src = l1b; si = i - P_L1B; }
  else if (i < P_L2B)   { src = l2g; si = i - P_L2G; }
  else if (i < P_BQ)    { src = l2b; si = i - P_L2B; }
  else if (i < P_BK)    { src = pbq; si = i - P_BQ; }
  else if (i < P_BV)    { src = pbk; si = i - P_BK; }
  else if (i < P_BO)    { src = pbv; si = i - P_BV; }
  else if (i < P_B1)    { src = pbo; si = i - P_BO; }
  else if (i < P_B2)    { src = pb1; si = i - P_B1; }
  else if (i < P_FQB)   { src = pb2; si = i - P_B2; }
  else if (i < P_TOT) {
    int j = i - P_FQB, l = j / 2304, c = j % 2304;
    src = (c < 768) ? pbq : (c < 1536 ? pbk : pbv);
    si = l * 768 + (c % 768);
  }
  else return;
  P[i] = flag[0] ? f2bf(((const float*)src)[si]) : ((const u16*)src)[si];
}

// ---------------- positional encoding ----------------
__global__ void posenc_kernel(const u16* __restrict__ P, float* __restrict__ pe) {
  int n = blockIdx.x;
  int r = n / 24, c = n % 24;
  const u16* re = P + P_RE;
  const u16* ce = P + P_CE;
  const u16* pw = P + P_PW;
  const u16* pb = P + P_PB;
  for (int d = threadIdx.x; d < SD_; d += 256) {
    float acc = bf2f(pb[d]);
    for (int s = 0; s < 32; ++s) {
      acc += bf2f(re[r * 32 + s]) * bf2f(pw[s * SD_ + d]);
      acc += bf2f(ce[c * 32 + s]) * bf2f(pw[(32 + s) * SD_ + d]);
    }
    pe[n * SD_ + d] = acc;
  }
}

// ---------------- relative position bias table [576][576] fp32 ----------------
__global__ void bias_kernel(const u16* __restrict__ P, float* __restrict__ biasT) {
  int i = blockIdx.x * 256 + threadIdx.x;
  if (i < SN * SN) {
    int qi = i / SN, kj = i % SN;
    int ri = qi / 24, ci = qi % 24, rj = kj / 24, cj = kj % 24;
    int idx = (ri - rj + 23) * 47 + (ci - cj + 23);
    biasT[i] = bf2f(P[P_REL + idx]);
  }
}

// ---------------- X = x + pe (fp32 residual), dual-dtype x ----------------
__global__ void xinit_kernel(const void* __restrict__ xin, const float* __restrict__ pe,
                             float* __restrict__ X, const int* __restrict__ flag) {
  int idx = (blockIdx.x * 256 + threadIdx.x) * 4;
  int b = blockIdx.y;
  float vx, vy, vz, vw;
  if (flag[0]) {
    float4 t = *(const float4*)((const float*)xin + (size_t)b * IMG + idx);
    vx = t.x; vy = t.y; vz = t.z; vw = t.w;
  } else {
    ushort4 t = *(const ushort4*)((const u16*)xin + (size_t)b * IMG + idx);
    vx = bf2f(t.x); vy = bf2f(t.y); vz = bf2f(t.z); vw = bf2f(t.w);
  }
  float4 p = *(const float4*)(pe + idx);
  float4 o;
  o.x = vx + p.x; o.y = vy + p.y; o.z = vz + p.z; o.w = vw + p.w;
  *(float4*)(X + (size_t)b * IMG + idx) = o;
}

// ---------------- weight transpose (dual-dtype): W[K][N] -> Wt[N][K] bf16 ----------------
__global__ void transpose_any(const void* __restrict__ W, size_t eOff,
                              u16* __restrict__ Wt, int K, int N,
                              const int* __restrict__ flag) {
  __shared__ u16 tile[64][65];
  const int fp32 = flag[0];
  int n0 = blockIdx.x * 64, k0 = blockIdx.y * 64;
  int tx = threadIdx.x, ty = threadIdx.y;
#pragma unroll
  for (int j = 0; j < 16; ++j) {
    int k = ty + 4 * j;
    size_t si = eOff + (size_t)(k0 + k) * N + n0 + tx;
    tile[k][tx] = fp32 ? f2bf(((const float*)W)[si]) : ((const u16*)W)[si];
  }
  __syncthreads();
#pragma unroll
  for (int j = 0; j < 16; ++j) {
    int n = ty + 4 * j;
    Wt[(size_t)(n0 + n) * K + k0 + tx] = tile[tx][n];
  }
}

// ---------------- LayerNorm: fp32 X row -> bf16 ----------------
__global__ __launch_bounds__(256) void ln_kernel(const float* __restrict__ X,
                                                 const u16* __restrict__ g,
                                                 const u16* __restrict__ bb,
                                                 u16* __restrict__ Outn) {
  int row = blockIdx.x * 4 + (threadIdx.x >> 6);
  int lane = threadIdx.x & 63;
  const float* xr = X + (size_t)row * SD_;
  float4 v[3];
  float s = 0.f, sq = 0.f;
#pragma unroll
  for (int i = 0; i < 3; ++i) {
    v[i] = *(const float4*)(xr + i * 256 + lane * 4);
    s += v[i].x + v[i].y + v[i].z + v[i].w;
    sq += v[i].x * v[i].x + v[i].y * v[i].y + v[i].z * v[i].z + v[i].w * v[i].w;
  }
#pragma unroll
  for (int o = 1; o < 64; o <<= 1) {
    s += __shfl_xor(s, o, 64);
    sq += __shfl_xor(sq, o, 64);
  }
  float mean = s * (1.0f / 768.0f);
  float var = sq * (1.0f / 768.0f) - mean * mean;
  float rstd = rsqrtf(fmaxf(var, 0.f) + 1e-5f);
  u16* orow = Outn + (size_t)row * SD_;
#pragma unroll
  for (int i = 0; i < 3; ++i) {
    int d = i * 256 + lane * 4;
    ushort4 gv = *(const ushort4*)(g + d);
    ushort4 bv = *(const ushort4*)(bb + d);
    ushort4 ov;
    ov.x = f2bf((v[i].x - mean) * rstd * bf2f(gv.x) + bf2f(bv.x));
    ov.y = f2bf((v[i].y - mean) * rstd * bf2f(gv.y) + bf2f(bv.y));
    ov.z = f2bf((v[i].z - mean) * rstd * bf2f(gv.z) + bf2f(bv.z));
    ov.w = f2bf((v[i].w - mean) * rstd * bf2f(gv.w) + bf2f(bv.w));
    *(ushort4*)(orow + d) = ov;
  }
}

// ---------------- GEMM: C = A[M,K] @ Bt[N,K]^T ----------------
// mode 0: Out=bf16(C+bias)  1: Out=bf16(gelu_exact(C+bias))  2: Xres += C+bias (fp32)
__global__ __launch_bounds__(256) void gemm_bt(const u16* __restrict__ A,
                                               const u16* __restrict__ Bt,
                                               const u16* __restrict__ bias,
                                               u16* __restrict__ Out,
                                               float* __restrict__ Xres,
                                               int Ncols, int K, int mode) {
  __shared__ __align__(16) u16 As[128 * 32];
  __shared__ __align__(16) u16 Bs[128 * 32];
  const int tid = threadIdx.x;
  const int lane = tid & 63;
  const int wave = tid >> 6;
  const int wm = wave & 1, wn = wave >> 1;
  const int bn = blockIdx.x, bm = blockIdx.y;
  const int m16 = lane & 15, q8 = (lane >> 4) * 8;
  f32x4 acc[4][4] = {};
  const size_t Abase = (size_t)(bm * 128) * K;
  const size_t Bbase = (size_t)(bn * 128) * K;

  for (int kb = 0; kb < K; kb += 32) {
    __syncthreads();
#pragma unroll
    for (int i = 0; i < 2; ++i) {
      int c = tid + i * 256;
      int row = c >> 2, ko = (c & 3) * 8;
      *(uint4*)(As + row * 32 + ko) = *(const uint4*)(A + Abase + (size_t)row * K + kb + ko);
      *(uint4*)(Bs + row * 32 + ko) = *(const uint4*)(Bt + Bbase + (size_t)row * K + kb + ko);
    }
    __syncthreads();
    frag af[4], bf[4];
#pragma unroll
    for (int t = 0; t < 4; ++t)
      af[t] = *(const frag*)(As + (wm * 64 + t * 16 + m16) * 32 + q8);
#pragma unroll
    for (int t = 0; t < 4; ++t)
      bf[t] = *(const frag*)(Bs + (wn * 64 + t * 16 + m16) * 32 + q8);
#pragma unroll
    for (int i = 0; i < 4; ++i)
#pragma unroll
      for (int j = 0; j < 4; ++j)
        acc[i][j] = MFMA16(af[i], bf[j], acc[i][j]);
  }

  const int r4 = (lane >> 4) * 4;
#pragma unroll
  for (int j = 0; j < 4; ++j) {
    int col = bn * 128 + wn * 64 + j * 16 + m16;
    float bv = bf2f(bias[col]);
#pragma unroll
    for (int i = 0; i < 4; ++i) {
      int row0 = bm * 128 + wm * 64 + i * 16 + r4;
#pragma unroll
      for (int r = 0; r < 4; ++r) {
        float v = acc[i][j][r] + bv;
        size_t off = (size_t)(row0 + r) * Ncols + col;
        if (mode == 0) {
          Out[off] = f2bf(v);
        } else if (mode == 1) {
          v = 0.5f * v * (1.0f + erff(v * 0.70710678118654752f));
          Out[off] = f2bf(v);
        } else {
          Xres[off] += v;
        }
      }
    }
  }
}

// ---------------- flash attention: block = (64-query tile, head, local batch) ----------------
// QKV chunk-local [mR][2304]: Q at h*96, K at 768+h*96, V at 1536+h*96.
// Out = full [18432][768] bf16 buffer.
__global__ __launch_bounds__(256) void attn_flash(const u16* __restrict__ QKV,
                                                  const float* __restrict__ biasT,
                                                  u16* __restrict__ Out, int b0) {
  __shared__ __align__(16) u16 Ks[64 * 104];   // K tile [key][d], stride 104 (2-way free)
  __shared__ __align__(16) u16 Vt[96 * 72];    // V^T tile [d][key], stride 72
  __shared__ __align__(16) u16 Ps[64 * 72];    // P tile [q][key], stride 72
  const int tid = threadIdx.x, lane = tid & 63, w = tid >> 6;
  const int m16 = lane & 15, q4 = lane >> 4;   // q4 in 0..3
  const int qt = blockIdx.x, h = blockIdx.y, bl = blockIdx.z;
  const int q0 = qt * 64;
  const int row0 = bl * SN;                    // chunk-local row base
  const float scale = 0.10206207261596575f;    // 96^-0.5

  // Q fragments in registers: rows w*16+m16, k = ks*32 + q4*8 .. +8
  frag aq[3];
  {
    const u16* qptr = QKV + (size_t)(row0 + q0 + w * 16 + m16) * QKVS + h * SHD;
#pragma unroll
    for (int ks = 0; ks < 3; ++ks) aq[ks] = *(const frag*)(qptr + ks * 32 + q4 * 8);
  }

  f32x4 oacc[6] = {};
  float mrun[4], lrun[4];
#pragma unroll
  for (int r = 0; r < 4; ++r) { mrun[r] = -1e30f; lrun[r] = 0.f; }

  for (int kt = 0; kt < 9; ++kt) {
    __syncthreads();
    // stage K tile [64 keys][96] and V^T tile [96][64 keys]
    for (int c = tid; c < 768; c += 256) {
      int key = c / 12, off = (c % 12) * 8;
      *(uint4*)(Ks + key * 104 + off) =
          *(const uint4*)(QKV + (size_t)(row0 + kt * 64 + key) * QKVS + 768 + h * SHD + off);
    }
    for (int c = tid; c < 768; c += 256) {
      int key = c / 12, off = (c % 12) * 8;
      uint4 u = *(const uint4*)(QKV + (size_t)(row0 + kt * 64 + key) * QKVS + 1536 + h * SHD + off);
      u16 tmp[8]; *(uint4*)tmp = u;
#pragma unroll
      for (int j = 0; j < 8; ++j) Vt[(off + j) * 72 + key] = tmp[j];
    }
    __syncthreads();

    // S tile: this wave's 16 q-rows x 64 keys
    f32x4 sa[4];
#pragma unroll
    for (int nt = 0; nt < 4; ++nt) {
      sa[nt] = (f32x4){0.f, 0.f, 0.f, 0.f};
#pragma unroll
      for (int ks = 0; ks < 3; ++ks) {
        frag bk = *(const frag*)(Ks + (nt * 16 + m16) * 104 + ks * 32 + q4 * 8);
        sa[nt] = MFMA16(aq[ks], bk, sa[nt]);
      }
    }

    // online softmax; lane holds rows (q4*4+r), cols nt*16+m16
    float sv[4][4], mnew[4];
#pragma unroll
    for (int r = 0; r < 4; ++r) {
      int grow = q0 + w * 16 + q4 * 4 + r;
      const float* brow = biasT + (size_t)grow * SN + kt * 64;
      float mx = mrun[r];
#pragma unroll
      for (int nt = 0; nt < 4; ++nt) {
        float s = sa[nt][r] * scale + brow[nt * 16 + m16];
        sv[r][nt] = s;
        mx = fmaxf(mx, s);
      }
#pragma unroll
      for (int o = 1; o < 16; o <<= 1) mx = fmaxf(mx, __shfl_xor(mx, o, 64));
      mnew[r] = mx;
    }
#pragma unroll
    for (int r = 0; r < 4; ++r) {
      float alpha = __expf(mrun[r] - mnew[r]);
      mrun[r] = mnew[r];
      float psum = 0.f;
#pragma unroll
      for (int nt = 0; nt < 4; ++nt) {
        float p = __expf(sv[r][nt] - mnew[r]);
        psum += p;
        Ps[(w * 16 + q4 * 4 + r) * 72 + nt * 16 + m16] = f2bf(p);
      }
#pragma unroll
      for (int o = 1; o < 16; o <<= 1) psum += __shfl_xor(psum, o, 64);
      lrun[r] = lrun[r] * alpha + psum;
#pragma unroll
      for (int dt = 0; dt < 6; ++dt) oacc[dt][r] *= alpha;
    }
    __syncthreads();

    // O += P @ V : A = Ps rows w*16+m16, B = Vt
#pragma unroll
    for (int ch = 0; ch < 2; ++ch) {
      frag ap = *(const frag*)(Ps + (w * 16 + m16) * 72 + ch * 32 + q4 * 8);
#pragma unroll
      for (int dt = 0; dt < 6; ++dt) {
        frag bv = *(const frag*)(Vt + (dt * 16 + m16) * 72 + ch * 32 + q4 * 8);
        oacc[dt] = MFMA16(ap, bv, oacc[dt]);
      }
    }
  }

#pragma unroll
  for (int r = 0; r < 4; ++r) {
    float inv = 1.0f / lrun[r];
    size_t obase = ((size_t)((b0 + bl) * SN + q0 + w * 16 + q4 * 4 + r)) * SD_ + h * SHD;
#pragma unroll
    for (int dt = 0; dt < 6; ++dt)
      Out[obase + dt * 16 + m16] = f2bf(oacc[dt][r] * inv);
  }
}

// ---------------- final output: fp32 X -> d_out in detected dtype ----------------
__global__ void castout_kernel(const float* __restrict__ X, void* __restrict__ out,
                               const int* __restrict__ flag) {
  int i = (blockIdx.x * 256 + threadIdx.x) * 4;
  float4 v = *(const float4*)(X + i);
  if (flag[0]) {
    *(float4*)((float*)out + i) = v;
  } else {
    ushort4 o;
    o.x = f2bf(v.x); o.y = f2bf(v.y); o.z = f2bf(v.z); o.w = f2bf(v.w);
    *(ushort4*)((u16*)out + i) = o;
  }
}

// ---------------- launcher ----------------
extern "C" void kernel_launch(void* const* d_in, const int* in_sizes, int n_in,
                              void* d_out, int out_size, void* d_ws, size_t ws_size,
                              hipStream_t stream) {
  const void* x_in      = d_in[0];
  const void* row_embed = d_in[1];
  const void* col_embed = d_in[2];
  const void* pos_w     = d_in[3];
  const void* pos_b     = d_in[4];
  const void* rel_bias  = d_in[5];
  const void* ln1_g = d_in[6];
  const void* ln1_b = d_in[7];
  const void* ln2_g = d_in[8];
  const void* ln2_b = d_in[9];
  const void* Wq = d_in[10];
  const void* bq = d_in[11];
  const void* Wk = d_in[12];
  const void* bk = d_in[13];
  const void* Wv = d_in[14];
  const void* bv = d_in[15];
  const void* Wo = d_in[16];
  const void* bo = d_in[17];
  const void* W1 = d_in[18];
  const void* b1 = d_in[19];
  const void* W2 = d_in[20];
  const void* b2 = d_in[21];

  // tiers: A (ws>=140 MB): BC=16/RC=9216 (~131 MB); B: BC=8/RC=4608 (~103 MB, proven)
  const bool tierA = ws_size >= (size_t)140000000;
  const int BC = tierA ? 16 : 8;
  const int RC = tierA ? 9216 : 4608;
  const int mR = BC * SN;                       // rows per attention chunk
  const size_t qkvB = (size_t)mR * QKVS * 2;
  size_t bigB = qkvB;
  { size_t hB = (size_t)RC * SMLP * 2; if (hB > bigB) bigB = hB; }

  char* ws = (char*)d_ws;
  size_t off = 0;
  auto alloc = [&](size_t bytes) -> void* {
    void* p = ws + off;
    off += (bytes + 255) & ~(size_t)255;
    return p;
  };

  int*   flag = (int*)alloc(256);
  float* X    = (float*)alloc((size_t)BN_ * SD_ * 4);   // 56.6 MB fp32 residual
  char*  big  = (char*)alloc(bigB);                      // QKV chunk / MLP hidden chunk
  u16* QKVc = (u16*)big;
  u16* Hbuf = (u16*)big;
  float* pe    = (float*)alloc((size_t)SN * SD_ * 4);
  float* biasT = (float*)alloc((size_t)SN * SN * 4);
  u16* P     = (u16*)alloc((size_t)P_TOT * 2 + 256);
  u16* WqkvT = (u16*)alloc((size_t)QKVS * SD_ * 2);      // fused [2304][768]
  u16* WoT   = (u16*)alloc((size_t)SD_ * SD_ * 2);
  u16* W1T   = (u16*)alloc((size_t)SD_ * SMLP * 2);
  u16* W2T   = (u16*)alloc((size_t)SMLP * SD_ * 2);
  u16* Nfull = (u16*)d_out;                              // LN-out / attn-out, 28.3 MB free

  detect_kernel<<<1, 64, 0, stream>>>(ln1_g, flag);
  canon_params<<<(P_TOT + 255) / 256, 256, 0, stream>>>(
      row_embed, col_embed, pos_w, pos_b, rel_bias,
      ln1_g, ln1_b, ln2_g, ln2_b, bq, bk, bv, bo, b1, b2, P, flag);

  posenc_kernel<<<SN, 256, 0, stream>>>(P, pe);
  bias_kernel<<<(SN * SN + 255) / 256, 256, 0, stream>>>(P, biasT);
  xinit_kernel<<<dim3(IMG / 1024, SB), 256, 0, stream>>>(x_in, pe, X, flag);

  dim3 tb(64, 4);
  for (int l = 0; l < 2; ++l) {
    const size_t wOff = (size_t)l * SD_ * SD_;
    const size_t w1Off = (size_t)l * SD_ * SMLP;
    transpose_any<<<dim3(12, 12), tb, 0, stream>>>(Wq, wOff, WqkvT, SD_, SD_, flag);
    transpose_any<<<dim3(12, 12), tb, 0, stream>>>(Wk, wOff, WqkvT + SD_ * SD_, SD_, SD_, flag);
    transpose_any<<<dim3(12, 12), tb, 0, stream>>>(Wv, wOff, WqkvT + 2 * SD_ * SD_, SD_, SD_, flag);
    transpose_any<<<dim3(12, 12), tb, 0, stream>>>(Wo, wOff, WoT, SD_, SD_, flag);
    transpose_any<<<dim3(48, 12), tb, 0, stream>>>(W1, w1Off, W1T, SD_, SMLP, flag);
    transpose_any<<<dim3(12, 48), tb, 0, stream>>>(W2, w1Off, W2T, SMLP, SD_, flag);

    // LN1 over all rows -> Nfull
    ln_kernel<<<BN_ / 4, 256, 0, stream>>>(X, P + P_L1G + l * SD_, P + P_L1B + l * SD_, Nfull);

    // fused QKV + flash attention, chunked over batch; attn overwrites Nfull rows in place
    for (int c = 0; c < SB / BC; ++c) {
      const size_t r0 = (size_t)c * mR;
      gemm_bt<<<dim3(QKVS / 128, mR / 128), 256, 0, stream>>>(
          Nfull + r0 * SD_, WqkvT, P + P_FQB + l * QKVS, QKVc, nullptr, QKVS, SD_, 0);
      attn_flash<<<dim3(SN / 64, SH, BC), 256, 0, stream>>>(QKVc, biasT, Nfull, c * BC);
    }
    // Wo over all rows
    gemm_bt<<<dim3(SD_ / 128, BN_ / 128), 256, 0, stream>>>(
        Nfull, WoT, P + P_BO + l * SD_, nullptr, X, SD_, SD_, 2);

    // LN2 over all rows -> Nfull
    ln_kernel<<<BN_ / 4, 256, 0, stream>>>(X, P + P_L2G + l * SD_, P + P_L2B + l * SD_, Nfull);

    // MLP, chunked over rows
    for (int c = 0; c < BN_ / RC; ++c) {
      const size_t r0 = (size_t)c * RC;
      gemm_bt<<<dim3(SMLP / 128, RC / 128), 256, 0, stream>>>(
          Nfull + r0 * SD_, W1T, P + P_B1 + l * SMLP, Hbuf, nullptr, SMLP, SD_, 1);
      gemm_bt<<<dim3(SD_ / 128, RC / 128), 256, 0, stream>>>(
          Hbuf, W2T, P + P_B2 + l * SD_, nullptr, X + r0 * SD_, SD_, SMLP, 2);
    }
  }

  castout_kernel<<<(size_t)BN_ * SD_ / 1024, 256, 0, stream>>>(X, d_out, flag);
}

// Round 6
// 2000.368 us; speedup vs baseline: 1.7318x; 1.0064x over previous
//
#include <hip/hip_runtime.h>
#include <hip/hip_bf16.h>
#include <cstdint>
#include <cstddef>

typedef unsigned short u16;
using frag  = __attribute__((ext_vector_type(8))) short;   // 8 x bf16
using f32x4 = __attribute__((ext_vector_type(4))) float;   // 4 x fp32 acc

#define DEV __device__ __forceinline__

DEV float bf2f(u16 u) { union { unsigned int i; float f; } x; x.i = ((unsigned int)u) << 16; return x.f; }
DEV u16 f2bf(float f) {
  union { float f; unsigned int i; } x; x.f = f;
  unsigned int r = x.i + 0x7fffu + ((x.i >> 16) & 1u);
  return (u16)(r >> 16);
}

#define MFMA16(a, b, c) __builtin_amdgcn_mfma_f32_16x16x32_bf16((a), (b), (c), 0, 0, 0)

// async global->LDS, 16 B per lane; LDS dest must be wave-uniform base + lane*16.
// CK-style addrspace handling: inttoptr of the generic pointer value (LDS offset = low 32 bits).
DEV void cp16_g2l(const u16* g, u16* l) {
  __builtin_amdgcn_global_load_lds(
      reinterpret_cast<const __attribute__((address_space(1))) unsigned int*>(
          reinterpret_cast<uintptr_t>(g)),
      reinterpret_cast<__attribute__((address_space(3))) unsigned int*>(
          reinterpret_cast<uintptr_t>(l)),
      16, 0, 0);
}

// B=32 N=576 D=768 H=8 HD=96 MLP=3072 L=2 GRID=24 SD=64
#define SB   32
#define SN   576
#define SD_  768
#define SH   8
#define SHD  96
#define SMLP 3072
#define BN_  (SB * SN)          // 18432 rows
#define IMG  (SN * SD_)         // 442368
#define QKVS 2304               // fused QKV row stride

// ---- bf16 param-mirror block offsets (elements) ----
#define P_RE   0
#define P_CE   768
#define P_PW   1536
#define P_PB   50688
#define P_REL  51456
#define P_L1G  53696
#define P_L1B  55232
#define P_L2G  56768
#define P_L2B  58304
#define P_BQ   59840
#define P_BK   61376
#define P_BV   62912
#define P_BO   64448
#define P_B1   65984
#define P_B2   72128
#define P_FQB  73664            // fused qkv bias [L][2304]
#define P_TOT  78272

// ---------------- dtype detect: ln1_g[0] == 1.0 exactly ----------------
__global__ void detect_kernel(const void* probe, int* flag) {
  if (threadIdx.x == 0 && blockIdx.x == 0) {
    unsigned int w = *(const unsigned int*)probe;
    flag[0] = (w == 0x3F800000u) ? 1 : 0;   // 1 => inputs are fp32
  }
}

// ---------------- canonicalize small params into bf16 mirror ----------------
__global__ void canon_params(const void* re, const void* ce, const void* pw, const void* pb,
                             const void* rel, const void* l1g, const void* l1b,
                             const void* l2g, const void* l2b,
                             const void* pbq, const void* pbk, const void* pbv, const void* pbo,
                             const void* pb1, const void* pb2,
                             u16* __restrict__ P, const int* __restrict__ flag) {
  int i = blockIdx.x * 256 + threadIdx.x;
  const void* src; int si;
  if      (i < 768)     { src = re;  si = i; }
  else if (i < 1536)    { src = ce;  si = i - 768; }
  else if (i < 50688)   { src = pw;  si = i - 1536; }
  else if (i < 51456)   { src = pb;  si = i - 50688; }
  else if (i < 53665)   { src = rel; si = i - 51456; }
  else if (i < P_L1G)   { return; }
  else if (i < P_L1B)   { src = l1g; si = i - P_L1G; }
  else if (i < P_L2G)   { src = l1b; si = i - P_L1B; }
  else if (i < P_L2B)   { src = l2g; si = i - P_L2G; }
  else if (i < P_BQ)    { src = l2b; si = i - P_L2B; }
  else if (i < P_BK)    { src = pbq; si = i - P_BQ; }
  else if (i < P_BV)    { src = pbk; si = i - P_BK; }
  else if (i < P_BO)    { src = pbv; si = i - P_BV; }
  else if (i < P_B1)    { src = pbo; si = i - P_BO; }
  else if (i < P_B2)    { src = pb1; si = i - P_B1; }
  else if (i < P_FQB)   { src = pb2; si = i - P_B2; }
  else if (i < P_TOT) {
    int j = i - P_FQB, l = j / 2304, c = j % 2304;
    src = (c < 768) ? pbq : (c < 1536 ? pbk : pbv);
    si = l * 768 + (c % 768);
  }
  else return;
  P[i] = flag[0] ? f2bf(((const float*)src)[si]) : ((const u16*)src)[si];
}

// ---------------- positional encoding ----------------
__global__ void posenc_kernel(const u16* __restrict__ P, float* __restrict__ pe) {
  int n = blockIdx.x;
  int r = n / 24, c = n % 24;
  const u16* re = P + P_RE;
  const u16* ce = P + P_CE;
  const u16* pw = P + P_PW;
  const u16* pb = P + P_PB;
  for (int d = threadIdx.x; d < SD_; d += 256) {
    float acc = bf2f(pb[d]);
    for (int s = 0; s < 32; ++s) {
      acc += bf2f(re[r * 32 + s]) * bf2f(pw[s * SD_ + d]);
      acc += bf2f(ce[c * 32 + s]) * bf2f(pw[(32 + s) * SD_ + d]);
    }
    pe[n * SD_ + d] = acc;
  }
}

// ---------------- relative position bias table [576][576] fp32 ----------------
__global__ void bias_kernel(const u16* __restrict__ P, float* __restrict__ biasT) {
  int i = blockIdx.x * 256 + threadIdx.x;
  if (i < SN * SN) {
    int qi = i / SN, kj = i % SN;
    int ri = qi / 24, ci = qi % 24, rj = kj / 24, cj = kj % 24;
    int idx = (ri - rj + 23) * 47 + (ci - cj + 23);
    biasT[i] = bf2f(P[P_REL + idx]);
  }
}

// ---------------- X = x + pe (fp32 residual), dual-dtype x ----------------
__global__ void xinit_kernel(const void* __restrict__ xin, const float* __restrict__ pe,
                             float* __restrict__ X, const int* __restrict__ flag) {
  int idx = (blockIdx.x * 256 + threadIdx.x) * 4;
  int b = blockIdx.y;
  float vx, vy, vz, vw;
  if (flag[0]) {
    float4 t = *(const float4*)((const float*)xin + (size_t)b * IMG + idx);
    vx = t.x; vy = t.y; vz = t.z; vw = t.w;
  } else {
    ushort4 t = *(const ushort4*)((const u16*)xin + (size_t)b * IMG + idx);
    vx = bf2f(t.x); vy = bf2f(t.y); vz = bf2f(t.z); vw = bf2f(t.w);
  }
  float4 p = *(const float4*)(pe + idx);
  float4 o;
  o.x = vx + p.x; o.y = vy + p.y; o.z = vz + p.z; o.w = vw + p.w;
  *(float4*)(X + (size_t)b * IMG + idx) = o;
}

// ---------------- weight transpose (dual-dtype): W[K][N] -> Wt[N][K] bf16 ----------------
__global__ void transpose_any(const void* __restrict__ W, size_t eOff,
                              u16* __restrict__ Wt, int K, int N,
                              const int* __restrict__ flag) {
  __shared__ u16 tile[64][65];
  const int fp32 = flag[0];
  int n0 = blockIdx.x * 64, k0 = blockIdx.y * 64;
  int tx = threadIdx.x, ty = threadIdx.y;
#pragma unroll
  for (int j = 0; j < 16; ++j) {
    int k = ty + 4 * j;
    size_t si = eOff + (size_t)(k0 + k) * N + n0 + tx;
    tile[k][tx] = fp32 ? f2bf(((const float*)W)[si]) : ((const u16*)W)[si];
  }
  __syncthreads();
#pragma unroll
  for (int j = 0; j < 16; ++j) {
    int n = ty + 4 * j;
    Wt[(size_t)(n0 + n) * K + k0 + tx] = tile[tx][n];
  }
}

// ---------------- LayerNorm: fp32 X row -> bf16 ----------------
__global__ __launch_bounds__(256) void ln_kernel(const float* __restrict__ X,
                                                 const u16* __restrict__ g,
                                                 const u16* __restrict__ bb,
                                                 u16* __restrict__ Outn) {
  int row = blockIdx.x * 4 + (threadIdx.x >> 6);
  int lane = threadIdx.x & 63;
  const float* xr = X + (size_t)row * SD_;
  float4 v[3];
  float s = 0.f, sq = 0.f;
#pragma unroll
  for (int i = 0; i < 3; ++i) {
    v[i] = *(const float4*)(xr + i * 256 + lane * 4);
    s += v[i].x + v[i].y + v[i].z + v[i].w;
    sq += v[i].x * v[i].x + v[i].y * v[i].y + v[i].z * v[i].z + v[i].w * v[i].w;
  }
#pragma unroll
  for (int o = 1; o < 64; o <<= 1) {
    s += __shfl_xor(s, o, 64);
    sq += __shfl_xor(sq, o, 64);
  }
  float mean = s * (1.0f / 768.0f);
  float var = sq * (1.0f / 768.0f) - mean * mean;
  float rstd = rsqrtf(fmaxf(var, 0.f) + 1e-5f);
  u16* orow = Outn + (size_t)row * SD_;
#pragma unroll
  for (int i = 0; i < 3; ++i) {
    int d = i * 256 + lane * 4;
    ushort4 gv = *(const ushort4*)(g + d);
    ushort4 bv = *(const ushort4*)(bb + d);
    ushort4 ov;
    ov.x = f2bf((v[i].x - mean) * rstd * bf2f(gv.x) + bf2f(bv.x));
    ov.y = f2bf((v[i].y - mean) * rstd * bf2f(gv.y) + bf2f(bv.y));
    ov.z = f2bf((v[i].z - mean) * rstd * bf2f(gv.z) + bf2f(bv.z));
    ov.w = f2bf((v[i].w - mean) * rstd * bf2f(gv.w) + bf2f(bv.w));
    *(ushort4*)(orow + d) = ov;
  }
}

// ---------------- GEMM: C = A[M,K] @ Bt[N,K]^T ----------------
// mode 0: Out=bf16(C+bias)  1: Out=bf16(gelu_exact(C+bias))  2: Xres += C+bias (fp32)
__global__ __launch_bounds__(256) void gemm_bt(const u16* __restrict__ A,
                                               const u16* __restrict__ Bt,
                                               const u16* __restrict__ bias,
                                               u16* __restrict__ Out,
                                               float* __restrict__ Xres,
                                               int Ncols, int K, int mode) {
  __shared__ __align__(16) u16 As[128 * 32];
  __shared__ __align__(16) u16 Bs[128 * 32];
  const int tid = threadIdx.x;
  const int lane = tid & 63;
  const int wave = tid >> 6;
  const int wm = wave & 1, wn = wave >> 1;
  const int bn = blockIdx.x, bm = blockIdx.y;
  const int m16 = lane & 15, q8 = (lane >> 4) * 8;
  f32x4 acc[4][4] = {};
  // staging addresses: chunk c = tid + i*256 -> row c>>2, k-off (c&3)*8, LDS elem c*8
  const int r0s = tid >> 2, k0s = (tid & 3) * 8;
  const u16* Ag = A + (size_t)(bm * 128) * K + (size_t)r0s * K + k0s;
  const u16* Bg = Bt + (size_t)(bn * 128) * K + (size_t)r0s * K + k0s;
  u16* As0 = As + tid * 8;
  u16* Bs0 = Bs + tid * 8;
  const size_t rowStep = (size_t)64 * K;   // +256 chunks = +64 rows

  for (int kb = 0; kb < K; kb += 32) {
    __syncthreads();
    cp16_g2l(Ag + kb, As0);
    cp16_g2l(Ag + kb + rowStep, As0 + 2048);
    cp16_g2l(Bg + kb, Bs0);
    cp16_g2l(Bg + kb + rowStep, Bs0 + 2048);
    __syncthreads();
    frag af[4], bf[4];
#pragma unroll
    for (int t = 0; t < 4; ++t)
      af[t] = *(const frag*)(As + (wm * 64 + t * 16 + m16) * 32 + q8);
#pragma unroll
    for (int t = 0; t < 4; ++t)
      bf[t] = *(const frag*)(Bs + (wn * 64 + t * 16 + m16) * 32 + q8);
#pragma unroll
    for (int i = 0; i < 4; ++i)
#pragma unroll
      for (int j = 0; j < 4; ++j)
        acc[i][j] = MFMA16(af[i], bf[j], acc[i][j]);
  }

  const int r4 = (lane >> 4) * 4;
#pragma unroll
  for (int j = 0; j < 4; ++j) {
    int col = bn * 128 + wn * 64 + j * 16 + m16;
    float bv = bf2f(bias[col]);
#pragma unroll
    for (int i = 0; i < 4; ++i) {
      int row0 = bm * 128 + wm * 64 + i * 16 + r4;
#pragma unroll
      for (int r = 0; r < 4; ++r) {
        float v = acc[i][j][r] + bv;
        size_t off = (size_t)(row0 + r) * Ncols + col;
        if (mode == 0) {
          Out[off] = f2bf(v);
        } else if (mode == 1) {
          v = 0.5f * v * (1.0f + erff(v * 0.70710678118654752f));
          Out[off] = f2bf(v);
        } else {
          Xres[off] += v;
        }
      }
    }
  }
}

// ---------------- flash attention: block = (64-query tile, head, local batch) ----------------
// QKV chunk-local [mR][2304]: Q at h*96, K at 768+h*96, V at 1536+h*96.
__global__ __launch_bounds__(256) void attn_flash(const u16* __restrict__ QKV,
                                                  const float* __restrict__ biasT,
                                                  u16* __restrict__ Out, int b0) {
  __shared__ __align__(16) u16 Ks[64 * 104];   // K tile [key][d], stride 104
  __shared__ __align__(16) u16 Vt[96 * 72];    // V^T tile [d][key], stride 72
  __shared__ __align__(16) u16 Ps[64 * 72];    // P tile [q][key], stride 72
  const int tid = threadIdx.x, lane = tid & 63, w = tid >> 6;
  const int m16 = lane & 15, q4 = lane >> 4;
  const int qt = blockIdx.x, h = blockIdx.y, bl = blockIdx.z;
  const int q0 = qt * 64;
  const int row0 = bl * SN;
  const float scale = 0.10206207261596575f;    // 96^-0.5

  frag aq[3];
  {
    const u16* qptr = QKV + (size_t)(row0 + q0 + w * 16 + m16) * QKVS + h * SHD;
#pragma unroll
    for (int ks = 0; ks < 3; ++ks) aq[ks] = *(const frag*)(qptr + ks * 32 + q4 * 8);
  }

  f32x4 oacc[6] = {};
  float mrun[4], lrun[4];
#pragma unroll
  for (int r = 0; r < 4; ++r) { mrun[r] = -1e30f; lrun[r] = 0.f; }

  for (int kt = 0; kt < 9; ++kt) {
    __syncthreads();
    for (int c = tid; c < 768; c += 256) {
      int key = c / 12, off = (c % 12) * 8;
      *(uint4*)(Ks + key * 104 + off) =
          *(const uint4*)(QKV + (size_t)(row0 + kt * 64 + key) * QKVS + 768 + h * SHD + off);
    }
    for (int c = tid; c < 768; c += 256) {
      int key = c / 12, off = (c % 12) * 8;
      uint4 u = *(const uint4*)(QKV + (size_t)(row0 + kt * 64 + key) * QKVS + 1536 + h * SHD + off);
      u16 tmp[8]; *(uint4*)tmp = u;
#pragma unroll
      for (int j = 0; j < 8; ++j) Vt[(off + j) * 72 + key] = tmp[j];
    }
    __syncthreads();

    f32x4 sa[4];
#pragma unroll
    for (int nt = 0; nt < 4; ++nt) {
      sa[nt] = (f32x4){0.f, 0.f, 0.f, 0.f};
#pragma unroll
      for (int ks = 0; ks < 3; ++ks) {
        frag bk = *(const frag*)(Ks + (nt * 16 + m16) * 104 + ks * 32 + q4 * 8);
        sa[nt] = MFMA16(aq[ks], bk, sa[nt]);
      }
    }

    float sv[4][4], mnew[4];
#pragma unroll
    for (int r = 0; r < 4; ++r) {
      int grow = q0 + w * 16 + q4 * 4 + r;
      const float* brow = biasT + (size_t)grow * SN + kt * 64;
      float mx = mrun[r];
#pragma unroll
      for (int nt = 0; nt < 4; ++nt) {
        float s = sa[nt][r] * scale + brow[nt * 16 + m16];
        sv[r][nt] = s;
        mx = fmaxf(mx, s);
      }
#pragma unroll
      for (int o = 1; o < 16; o <<= 1) mx = fmaxf(mx, __shfl_xor(mx, o, 64));
      mnew[r] = mx;
    }
#pragma unroll
    for (int r = 0; r < 4; ++r) {
      float alpha = __expf(mrun[r] - mnew[r]);
      mrun[r] = mnew[r];
      float psum = 0.f;
#pragma unroll
      for (int nt = 0; nt < 4; ++nt) {
        float p = __expf(sv[r][nt] - mnew[r]);
        psum += p;
        Ps[(w * 16 + q4 * 4 + r) * 72 + nt * 16 + m16] = f2bf(p);
      }
#pragma unroll
      for (int o = 1; o < 16; o <<= 1) psum += __shfl_xor(psum, o, 64);
      lrun[r] = lrun[r] * alpha + psum;
#pragma unroll
      for (int dt = 0; dt < 6; ++dt) oacc[dt][r] *= alpha;
    }
    __syncthreads();

#pragma unroll
    for (int ch = 0; ch < 2; ++ch) {
      frag ap = *(const frag*)(Ps + (w * 16 + m16) * 72 + ch * 32 + q4 * 8);
#pragma unroll
      for (int dt = 0; dt < 6; ++dt) {
        frag bv = *(const frag*)(Vt + (dt * 16 + m16) * 72 + ch * 32 + q4 * 8);
        oacc[dt] = MFMA16(ap, bv, oacc[dt]);
      }
    }
  }

#pragma unroll
  for (int r = 0; r < 4; ++r) {
    float inv = 1.0f / lrun[r];
    size_t obase = ((size_t)((b0 + bl) * SN + q0 + w * 16 + q4 * 4 + r)) * SD_ + h * SHD;
#pragma unroll
    for (int dt = 0; dt < 6; ++dt)
      Out[obase + dt * 16 + m16] = f2bf(oacc[dt][r] * inv);
  }
}

// ---------------- final output: fp32 X -> d_out in detected dtype ----------------
__global__ void castout_kernel(const float* __restrict__ X, void* __restrict__ out,
                               const int* __restrict__ flag) {
  int i = (blockIdx.x * 256 + threadIdx.x) * 4;
  float4 v = *(const float4*)(X + i);
  if (flag[0]) {
    *(float4*)((float*)out + i) = v;
  } else {
    ushort4 o;
    o.x = f2bf(v.x); o.y = f2bf(v.y); o.z = f2bf(v.z); o.w = f2bf(v.w);
    *(ushort4*)((u16*)out + i) = o;
  }
}

// ---------------- launcher ----------------
extern "C" void kernel_launch(void* const* d_in, const int* in_sizes, int n_in,
                              void* d_out, int out_size, void* d_ws, size_t ws_size,
                              hipStream_t stream) {
  const void* x_in      = d_in[0];
  const void* row_embed = d_in[1];
  const void* col_embed = d_in[2];
  const void* pos_w     = d_in[3];
  const void* pos_b     = d_in[4];
  const void* rel_bias  = d_in[5];
  const void* ln1_g = d_in[6];
  const void* ln1_b = d_in[7];
  const void* ln2_g = d_in[8];
  const void* ln2_b = d_in[9];
  const void* Wq = d_in[10];
  const void* bq = d_in[11];
  const void* Wk = d_in[12];
  const void* bk = d_in[13];
  const void* Wv = d_in[14];
  const void* bv = d_in[15];
  const void* Wo = d_in[16];
  const void* bo = d_in[17];
  const void* W1 = d_in[18];
  const void* b1 = d_in[19];
  const void* W2 = d_in[20];
  const void* b2 = d_in[21];

  // tiers: A (ws>=131 MB): BC=16/RC=9216 (~130.7 MB); B: BC=8/RC=4608 (~103 MB, proven)
  const bool tierA = ws_size >= (size_t)131000000;
  const int BC = tierA ? 16 : 8;
  const int RC = tierA ? 9216 : 4608;
  const int mR = BC * SN;
  const size_t qkvB = (size_t)mR * QKVS * 2;
  size_t bigB = qkvB;
  { size_t hB = (size_t)RC * SMLP * 2; if (hB > bigB) bigB = hB; }

  char* ws = (char*)d_ws;
  size_t off = 0;
  auto alloc = [&](size_t bytes) -> void* {
    void* p = ws + off;
    off += (bytes + 255) & ~(size_t)255;
    return p;
  };

  int*   flag = (int*)alloc(256);
  float* X    = (float*)alloc((size_t)BN_ * SD_ * 4);   // 56.6 MB fp32 residual
  char*  big  = (char*)alloc(bigB);                      // QKV chunk / MLP hidden chunk
  u16* QKVc = (u16*)big;
  u16* Hbuf = (u16*)big;
  float* pe    = (float*)alloc((size_t)SN * SD_ * 4);
  float* biasT = (float*)alloc((size_t)SN * SN * 4);
  u16* P     = (u16*)alloc((size_t)P_TOT * 2 + 256);
  u16* WqkvT = (u16*)alloc((size_t)QKVS * SD_ * 2);      // fused [2304][768]
  u16* WoT   = (u16*)alloc((size_t)SD_ * SD_ * 2);
  u16* W1T   = (u16*)alloc((size_t)SD_ * SMLP * 2);
  u16* W2T   = (u16*)alloc((size_t)SMLP * SD_ * 2);
  u16* Nfull = (u16*)d_out;                              // LN-out / attn-out in d_out

  detect_kernel<<<1, 64, 0, stream>>>(ln1_g, flag);
  canon_params<<<(P_TOT + 255) / 256, 256, 0, stream>>>(
      row_embed, col_embed, pos_w, pos_b, rel_bias,
      ln1_g, ln1_b, ln2_g, ln2_b, bq, bk, bv, bo, b1, b2, P, flag);

  posenc_kernel<<<SN, 256, 0, stream>>>(P, pe);
  bias_kernel<<<(SN * SN + 255) / 256, 256, 0, stream>>>(P, biasT);
  xinit_kernel<<<dim3(IMG / 1024, SB), 256, 0, stream>>>(x_in, pe, X, flag);

  dim3 tb(64, 4);
  for (int l = 0; l < 2; ++l) {
    const size_t wOff = (size_t)l * SD_ * SD_;
    const size_t w1Off = (size_t)l * SD_ * SMLP;
    transpose_any<<<dim3(12, 12), tb, 0, stream>>>(Wq, wOff, WqkvT, SD_, SD_, flag);
    transpose_any<<<dim3(12, 12), tb, 0, stream>>>(Wk, wOff, WqkvT + SD_ * SD_, SD_, SD_, flag);
    transpose_any<<<dim3(12, 12), tb, 0, stream>>>(Wv, wOff, WqkvT + 2 * SD_ * SD_, SD_, SD_, flag);
    transpose_any<<<dim3(12, 12), tb, 0, stream>>>(Wo, wOff, WoT, SD_, SD_, flag);
    transpose_any<<<dim3(48, 12), tb, 0, stream>>>(W1, w1Off, W1T, SD_, SMLP, flag);
    transpose_any<<<dim3(12, 48), tb, 0, stream>>>(W2, w1Off, W2T, SMLP, SD_, flag);

    // LN1 over all rows -> Nfull
    ln_kernel<<<BN_ / 4, 256, 0, stream>>>(X, P + P_L1G + l * SD_, P + P_L1B + l * SD_, Nfull);

    // fused QKV + flash attention, chunked over batch
    for (int c = 0; c < SB / BC; ++c) {
      const size_t r0 = (size_t)c * mR;
      gemm_bt<<<dim3(QKVS / 128, mR / 128), 256, 0, stream>>>(
          Nfull + r0 * SD_, WqkvT, P + P_FQB + l * QKVS, QKVc, nullptr, QKVS, SD_, 0);
      attn_flash<<<dim3(SN / 64, SH, BC), 256, 0, stream>>>(QKVc, biasT, Nfull, c * BC);
    }
    // Wo over all rows
    gemm_bt<<<dim3(SD_ / 128, BN_ / 128), 256, 0, stream>>>(
        Nfull, WoT, P + P_BO + l * SD_, nullptr, X, SD_, SD_, 2);

    // LN2 over all rows -> Nfull
    ln_kernel<<<BN_ / 4, 256, 0, stream>>>(X, P + P_L2G + l * SD_, P + P_L2B + l * SD_, Nfull);

    // MLP, chunked over rows
    for (int c = 0; c < BN_ / RC; ++c) {
      const size_t r0 = (size_t)c * RC;
      gemm_bt<<<dim3(SMLP / 128, RC / 128), 256, 0, stream>>>(
          Nfull + r0 * SD_, W1T, P + P_B1 + l * SMLP, Hbuf, nullptr, SMLP, SD_, 1);
      gemm_bt<<<dim3(SD_ / 128, RC / 128), 256, 0, stream>>>(
          Hbuf, W2T, P + P_B2 + l * SD_, nullptr, X + r0 * SD_, SD_, SMLP, 2);
    }
  }

  castout_kernel<<<(size_t)BN_ * SD_ / 1024, 256, 0, stream>>>(X, d_out, flag);
}